// Round 7
// baseline (242.630 us; speedup 1.0000x reference)
//
#include <hip/hip_runtime.h>
#include <hip/hip_fp16.h>
#include <math.h>

#define N_NODES 50000
#define E_EDGES 800000
#define ETOT    (E_EDGES + N_NODES)
#define SCAN_CHUNK 1024
#define SCAN_NB ((N_NODES + SCAN_CHUNK - 1) / SCAN_CHUNK)   // 49

// bucketed scatter params
#define BUCK_SHIFT 9
#define NBUCK ((N_NODES + (1 << BUCK_SHIFT) - 1) >> BUCK_SHIFT)   // 98
#define BS_EPT 16
#define BS_THREADS 256
#define BS_EPB (BS_THREADS * BS_EPT)                              // 4096
#define BS_NBLK ((ETOT + BS_EPB - 1) / BS_EPB)

// ---------------------------------------------------------------------------
// Register-tiled GEMM + alpha epilogue. H written as fp16 (gather payload).
// ---------------------------------------------------------------------------
template<int DIN, int DOUT>
__global__ __launch_bounds__(256)
void gemm_alpha_kernel(const float* __restrict__ X, const float* __restrict__ W,
                       const float* __restrict__ a_s, const float* __restrict__ a_d,
                       __half* __restrict__ H16, float* __restrict__ asrc,
                       float* __restrict__ adst)
{
    constexpr int COLG = DOUT / 4;
    constexpr int ROWG = 256 / COLG;
    constexpr int BM   = ROWG * 4;
    constexpr int K4   = DIN / 4;

    __shared__ float Xl[BM * DIN];
    __shared__ float Wl[DIN * DOUT];

    const int tid = threadIdx.x;
    const int row0b = blockIdx.x * BM;

    constexpr int WV = DIN * DOUT / 4;
    for (int i = tid; i < WV; i += 256)
        ((float4*)Wl)[i] = ((const float4*)W)[i];

    constexpr int XV = BM * K4;
    for (int i = tid; i < XV; i += 256) {
        int r  = i / K4;
        int j  = i % K4;
        int gr = row0b + r;
        float4 v = make_float4(0.f, 0.f, 0.f, 0.f);
        if (gr < N_NODES) v = ((const float4*)X)[gr * K4 + j];
        *(float4*)&Xl[r * DIN + ((j ^ ((r >> 2) & 7)) << 2)] = v;
    }
    __syncthreads();

    const int tx = tid % COLG;
    const int ty = tid / COLG;
    const int r0 = ty * 4;
    const int c0 = tx * 4;
    const int swz = ty & 7;

    float acc[4][4] = {};
    for (int kk = 0; kk < DIN; kk += 4) {
        float a[4][4], w[4][4];
        const int jk = ((kk >> 2) ^ swz) << 2;
#pragma unroll
        for (int i = 0; i < 4; ++i)
            *(float4*)a[i] = *(const float4*)&Xl[(r0 + i) * DIN + jk];
#pragma unroll
        for (int j = 0; j < 4; ++j)
            *(float4*)w[j] = *(const float4*)&Wl[(kk + j) * DOUT + c0];
#pragma unroll
        for (int i = 0; i < 4; ++i)
#pragma unroll
            for (int j = 0; j < 4; ++j)
                acc[i][j] = fmaf(a[i][0], w[0][j],
                            fmaf(a[i][1], w[1][j],
                            fmaf(a[i][2], w[2][j],
                            fmaf(a[i][3], w[3][j], acc[i][j]))));
    }

    float as4[4], ad4[4];
    *(float4*)as4 = *(const float4*)&a_s[c0];
    *(float4*)ad4 = *(const float4*)&a_d[c0];

#pragma unroll
    for (int i = 0; i < 4; ++i) {
        const int gr = row0b + r0 + i;
        float ps = acc[i][0] * as4[0] + acc[i][1] * as4[1] +
                   acc[i][2] * as4[2] + acc[i][3] * as4[3];
        float pd = acc[i][0] * ad4[0] + acc[i][1] * ad4[1] +
                   acc[i][2] * ad4[2] + acc[i][3] * ad4[3];
#pragma unroll
        for (int off = COLG / 2; off >= 1; off >>= 1) {
            ps += __shfl_xor(ps, off, 64);
            pd += __shfl_xor(pd, off, 64);
        }
        if (gr < N_NODES) {
            __half2 p01 = __floats2half2_rn(acc[i][0], acc[i][1]);
            __half2 p23 = __floats2half2_rn(acc[i][2], acc[i][3]);
            uint2 pk;
            pk.x = *(unsigned int*)&p01;
            pk.y = *(unsigned int*)&p23;
            *(uint2*)&H16[gr * DOUT + c0] = pk;
            if (tx == 0) { asrc[gr] = ps; adst[gr] = pd; }
        }
    }
}

// ---------------------------------------------------------------------------
// CSR build
// ---------------------------------------------------------------------------
__global__ __launch_bounds__(256)
void zero_kernel(int* __restrict__ deg, int* __restrict__ bcnt)
{
    int i = blockIdx.x * blockDim.x + threadIdx.x;
    if (i < N_NODES) deg[i] = 0;
    if (i < NBUCK)   bcnt[i] = 0;
}

// bucket histogram (LDS-local, 98 counters)
__global__ __launch_bounds__(BS_THREADS)
void hist_kernel(const int* __restrict__ ei, int* __restrict__ bcnt)
{
    __shared__ int lcnt[NBUCK];
    const int t = threadIdx.x;
    for (int i = t; i < NBUCK; i += BS_THREADS) lcnt[i] = 0;
    __syncthreads();
    const int e0 = blockIdx.x * BS_EPB;
#pragma unroll
    for (int k = 0; k < BS_EPT; ++k) {
        const int eid = e0 + k * BS_THREADS + t;
        if (eid < ETOT) {
            int dst = (eid < E_EDGES) ? ei[E_EDGES + eid] : (eid - E_EDGES);
            atomicAdd(&lcnt[dst >> BUCK_SHIFT], 1);
        }
    }
    __syncthreads();
    for (int i = t; i < NBUCK; i += BS_THREADS)
        if (lcnt[i] > 0) atomicAdd(&bcnt[i], lcnt[i]);
}

// exclusive scan of NBUCK bucket counts -> binscatter cursors
__global__ __launch_bounds__(128)
void scan98_kernel(const int* __restrict__ bcnt, int* __restrict__ cur)
{
    __shared__ int lds[128];
    const int t = threadIdx.x;
    const int v = (t < NBUCK) ? bcnt[t] : 0;
    lds[t] = v;
    __syncthreads();
    for (int off = 1; off < 128; off <<= 1) {
        int u = (t >= off) ? lds[t - off] : 0;
        __syncthreads();
        lds[t] += u;
        __syncthreads();
    }
    if (t < NBUCK) cur[t] = lds[t] - v;
}

// Phase A: bin edges into dst-buckets; per-(block,bucket) contiguous runs in tmp.
__global__ __launch_bounds__(BS_THREADS)
void binscatter_kernel(const int* __restrict__ ei, int* __restrict__ cur,
                       unsigned int* __restrict__ tmp)
{
    __shared__ int lcnt[NBUCK];
    __shared__ int lbase[NBUCK];
    const int t = threadIdx.x;
    for (int i = t; i < NBUCK; i += BS_THREADS) lcnt[i] = 0;
    __syncthreads();

    const int e0 = blockIdx.x * BS_EPB;
    unsigned int pk[BS_EPT];
    int rk[BS_EPT];
    int bk[BS_EPT];
#pragma unroll
    for (int k = 0; k < BS_EPT; ++k) {
        const int eid = e0 + k * BS_THREADS + t;
        bk[k] = -1;
        if (eid < ETOT) {
            int src, dst;
            if (eid < E_EDGES) { src = ei[eid]; dst = ei[E_EDGES + eid]; }
            else               { src = dst = eid - E_EDGES; }
            bk[k] = dst >> BUCK_SHIFT;
            pk[k] = ((unsigned int)dst << 16) | (unsigned int)src;
            rk[k] = atomicAdd(&lcnt[bk[k]], 1);
        }
    }
    __syncthreads();
    for (int i = t; i < NBUCK; i += BS_THREADS)
        if (lcnt[i] > 0) lbase[i] = atomicAdd(&cur[i], lcnt[i]);
    __syncthreads();
#pragma unroll
    for (int k = 0; k < BS_EPT; ++k)
        if (bk[k] >= 0) tmp[lbase[bk[k]] + rk[k]] = pk[k];
}

// deg from bucket-ordered tmp: atomics land in ~2KB L2-local windows
__global__ __launch_bounds__(256)
void deg_tmp_kernel(const unsigned int* __restrict__ tmp, int* __restrict__ deg)
{
    int i = blockIdx.x * blockDim.x + threadIdx.x;
    if (i < ETOT) atomicAdd(deg + (tmp[i] >> 16), 1);
}

__global__ __launch_bounds__(256)
void scan_part_kernel(const int* __restrict__ deg, int* __restrict__ bsum)
{
    __shared__ int lds[256];
    const int base = blockIdx.x * SCAN_CHUNK;
    int sum = 0;
    for (int i = threadIdx.x; i < SCAN_CHUNK; i += 256) {
        int idx = base + i;
        sum += (idx < N_NODES) ? deg[idx] : 0;
    }
    lds[threadIdx.x] = sum;
    __syncthreads();
    for (int off = 128; off >= 1; off >>= 1) {
        if (threadIdx.x < off) lds[threadIdx.x] += lds[threadIdx.x + off];
        __syncthreads();
    }
    if (threadIdx.x == 0) bsum[blockIdx.x] = lds[0];
}

__global__ __launch_bounds__(64)
void scan_top_kernel(int* __restrict__ bsum)
{
    const int t = threadIdx.x;
    int v = (t < SCAN_NB) ? bsum[t] : 0;
    for (int off = 1; off < 64; off <<= 1) {
        int u = __shfl_up(v, off, 64);
        if (t >= off) v += u;
    }
    int ex = __shfl_up(v, 1, 64);
    if (t == 0) ex = 0;
    if (t < SCAN_NB) bsum[t] = ex;
}

__global__ __launch_bounds__(256)
void scan_out_kernel(const int* __restrict__ deg, const int* __restrict__ bsum,
                     int* __restrict__ offs, int* __restrict__ woff)
{
    __shared__ int lds[256];
    const int t = threadIdx.x;
    const int idx0 = blockIdx.x * SCAN_CHUNK + t * 4;
    int v[4];
    int tsum = 0;
#pragma unroll
    for (int i = 0; i < 4; ++i) {
        int idx = idx0 + i;
        v[i] = (idx < N_NODES) ? deg[idx] : 0;
        tsum += v[i];
    }
    lds[t] = tsum;
    __syncthreads();
    for (int off = 1; off < 256; off <<= 1) {
        int u = (t >= off) ? lds[t - off] : 0;
        __syncthreads();
        lds[t] += u;
        __syncthreads();
    }
    int run = bsum[blockIdx.x] + ((t > 0) ? lds[t - 1] : 0);
#pragma unroll
    for (int i = 0; i < 4; ++i) {
        int idx = idx0 + i;
        if (idx < N_NODES) { offs[idx] = run; woff[idx] = run; run += v[i]; }
    }
    if (blockIdx.x == 0 && t == 0) offs[N_NODES] = ETOT;
}

// Phase B: tmp is bucket-clustered -> final scatter stays in hot L2 windows.
// csr keeps the packed (dst<<16|src) word.
__global__ __launch_bounds__(256)
void final_scatter_kernel(const unsigned int* __restrict__ tmp,
                          int* __restrict__ woff, unsigned int* __restrict__ csr_pk)
{
    int i = blockIdx.x * blockDim.x + threadIdx.x;
    if (i >= ETOT) return;
    unsigned int v = tmp[i];
    int pos = atomicAdd(woff + (v >> 16), 1);
    csr_pk[pos] = v;
}

// ---------------------------------------------------------------------------
// per-layer edge scores: p = exp(leakyrelu(asrc[src] + adst[dst])), once/edge
// ---------------------------------------------------------------------------
__global__ __launch_bounds__(256)
void edge_score_kernel(const unsigned int* __restrict__ csr_pk,
                       const float* __restrict__ asrc,
                       const float* __restrict__ adst,
                       float* __restrict__ pbuf)
{
    int i = blockIdx.x * blockDim.x + threadIdx.x;
    if (i >= ETOT) return;
    const unsigned int pk = csr_pk[i];
    float v = asrc[pk & 0xffffu] + adst[pk >> 16];
    v = (v > 0.f) ? v : 0.2f * v;
    pbuf[i] = __expf(fminf(v, 80.f));
}

// ---------------------------------------------------------------------------
// node_agg v4: scores precomputed; inner loop = pk/p broadcast loads +
// one 8B fp16 H gather + 4 fma. wave = FL feature-lanes x SLOTS edge-slots.
// ---------------------------------------------------------------------------
template<int DOUT, int ACT>
__global__ __launch_bounds__(256)
void node_agg_kernel(const int* __restrict__ offs,
                     const unsigned int* __restrict__ csr_pk,
                     const float* __restrict__ pbuf,
                     const __half* __restrict__ H16,
                     const float* __restrict__ b,
                     float* __restrict__ out)
{
    constexpr int FL    = DOUT / 4;    // 16 (dout=64) or 8 (dout=32)
    constexpr int SLOTS = 64 / FL;     // 4 or 8
    const int wv   = threadIdx.x >> 6;
    const int lane = threadIdx.x & 63;
    const int fl   = lane % FL;
    const int slot = lane / FL;
    const int node = blockIdx.x * 4 + wv;
    if (node >= N_NODES) return;

    const int beg = offs[node];
    const int end = offs[node + 1];
    const __half* __restrict__ Hf = H16 + fl * 4;

    float s = 0.f;
    float4 acc = make_float4(0.f, 0.f, 0.f, 0.f);

    for (int cb = beg; cb < end; cb += SLOTS) {
        const int eid = cb + slot;
        float p = 0.f;
        uint2 h8 = make_uint2(0u, 0u);
        if (eid < end) {
            const unsigned int pk = csr_pk[eid];
            p  = pbuf[eid];
            h8 = *(const uint2*)(Hf + (pk & 0xffffu) * DOUT);
        }
        const float2 f01 = __half22float2(*(const __half2*)&h8.x);
        const float2 f23 = __half22float2(*(const __half2*)&h8.y);
        s += p;
        acc.x = fmaf(p, f01.x, acc.x);
        acc.y = fmaf(p, f01.y, acc.y);
        acc.z = fmaf(p, f23.x, acc.z);
        acc.w = fmaf(p, f23.y, acc.w);
    }

#pragma unroll
    for (int off = FL; off < 64; off <<= 1) {
        s     += __shfl_xor(s, off, 64);
        acc.x += __shfl_xor(acc.x, off, 64);
        acc.y += __shfl_xor(acc.y, off, 64);
        acc.z += __shfl_xor(acc.z, off, 64);
        acc.w += __shfl_xor(acc.w, off, 64);
    }

    if (slot == 0) {
        const float4 bb = *(const float4*)&b[fl * 4];
        const float inv = 1.f / s;
        float4 v;
        v.x = acc.x * inv + bb.x;
        v.y = acc.y * inv + bb.y;
        v.z = acc.z * inv + bb.z;
        v.w = acc.w * inv + bb.w;
        if (ACT == 0) {
            v.x = fmaxf(v.x, 0.f); v.y = fmaxf(v.y, 0.f);
            v.z = fmaxf(v.z, 0.f); v.w = fmaxf(v.w, 0.f);
        } else {
            v.x = tanhf(v.x); v.y = tanhf(v.y);
            v.z = tanhf(v.z); v.w = tanhf(v.w);
        }
        *(float4*)&out[node * DOUT + fl * 4] = v;
    }
}

// ---------------------------------------------------------------------------

template<int DIN, int DOUT, int ACT>
static void run_layer(const float* X, const float* W, const float* a_s,
                      const float* a_d, const float* b,
                      const int* offs, const unsigned int* csr_pk,
                      float* pbuf, __half* H16, float* asrc, float* adst,
                      float* out, hipStream_t stream)
{
    constexpr int COLG = DOUT / 4;
    constexpr int BM = (256 / COLG) * 4;
    const int gemm_grid = (N_NODES + BM - 1) / BM;
    gemm_alpha_kernel<DIN, DOUT><<<gemm_grid, 256, 0, stream>>>(
        X, W, a_s, a_d, H16, asrc, adst);

    const int egrid = (ETOT + 255) / 256;
    edge_score_kernel<<<egrid, 256, 0, stream>>>(csr_pk, asrc, adst, pbuf);

    const int agg_grid = (N_NODES + 3) / 4;
    node_agg_kernel<DOUT, ACT><<<agg_grid, 256, 0, stream>>>(
        offs, csr_pk, pbuf, H16, b, out);
}

extern "C" void kernel_launch(void* const* d_in, const int* in_sizes, int n_in,
                              void* d_out, int out_size, void* d_ws, size_t ws_size,
                              hipStream_t stream)
{
    const float* x  = (const float*)d_in[0];
    const int*   ei = (const int*)d_in[1];
    const float* W0 = (const float*)d_in[2];
    const float* as0= (const float*)d_in[3];
    const float* ad0= (const float*)d_in[4];
    const float* b0 = (const float*)d_in[5];
    const float* W1 = (const float*)d_in[6];
    const float* as1= (const float*)d_in[7];
    const float* ad1= (const float*)d_in[8];
    const float* b1 = (const float*)d_in[9];
    const float* W2 = (const float*)d_in[10];
    const float* as2= (const float*)d_in[11];
    const float* ad2= (const float*)d_in[12];
    const float* b2 = (const float*)d_in[13];
    float* out = (float*)d_out;

    char* wsb = (char*)d_ws;
    auto take = [&](size_t bytes) {
        char* p = wsb;
        wsb += (bytes + 255) & ~size_t(255);
        return p;
    };
    __half* h16    = (__half*)take(sizeof(__half) * N_NODES * 64);
    float* buf_act = (float*)take(sizeof(float) * N_NODES * 64);
    float* pbuf    = (float*)take(sizeof(float) * ETOT);
    float* asrc    = (float*)take(sizeof(float) * N_NODES);
    float* adst    = (float*)take(sizeof(float) * N_NODES);
    int*   deg     = (int*)take(sizeof(int) * N_NODES);
    int*   offs    = (int*)take(sizeof(int) * (N_NODES + 1));
    int*   woff    = (int*)take(sizeof(int) * N_NODES);
    int*   bsum    = (int*)take(sizeof(int) * SCAN_NB);
    int*   bcnt    = (int*)take(sizeof(int) * NBUCK);
    int*   cur     = (int*)take(sizeof(int) * NBUCK);
    unsigned int* csr_pk = (unsigned int*)take(sizeof(unsigned int) * ETOT);
    // tmp aliases h16: dead before the first gemm writes H16
    unsigned int* tmp = (unsigned int*)h16;

    const int ngrid = (N_NODES + 255) / 256;
    const int egrid = (ETOT + 255) / 256;
    zero_kernel<<<ngrid, 256, 0, stream>>>(deg, bcnt);
    hist_kernel<<<BS_NBLK, BS_THREADS, 0, stream>>>(ei, bcnt);
    scan98_kernel<<<1, 128, 0, stream>>>(bcnt, cur);
    binscatter_kernel<<<BS_NBLK, BS_THREADS, 0, stream>>>(ei, cur, tmp);
    deg_tmp_kernel<<<egrid, 256, 0, stream>>>(tmp, deg);
    scan_part_kernel<<<SCAN_NB, 256, 0, stream>>>(deg, bsum);
    scan_top_kernel<<<1, 64, 0, stream>>>(bsum);
    scan_out_kernel<<<SCAN_NB, 256, 0, stream>>>(deg, bsum, offs, woff);
    final_scatter_kernel<<<egrid, 256, 0, stream>>>(tmp, woff, csr_pk);

    run_layer<128, 64, 0>(x, W0, as0, ad0, b0, offs, csr_pk, pbuf,
                          h16, asrc, adst, buf_act, stream);
    run_layer<64, 64, 0>(buf_act, W1, as1, ad1, b1, offs, csr_pk, pbuf,
                         h16, asrc, adst, buf_act, stream);
    run_layer<64, 32, 1>(buf_act, W2, as2, ad2, b2, offs, csr_pk, pbuf,
                         h16, asrc, adst, out, stream);
}

// Round 8
// 203.893 us; speedup vs baseline: 1.1900x; 1.1900x over previous
//
#include <hip/hip_runtime.h>
#include <hip/hip_fp16.h>
#include <math.h>

#define N_NODES 50000
#define E_EDGES 800000
#define ETOT    (E_EDGES + N_NODES)

// bucketed scatter params
#define BUCK_SHIFT 9
#define BUCK_SZ   (1 << BUCK_SHIFT)                               // 512
#define NBUCK ((N_NODES + BUCK_SZ - 1) >> BUCK_SHIFT)             // 98
#define BS_EPT 16
#define BS_THREADS 256
#define BS_EPB (BS_THREADS * BS_EPT)                              // 4096
#define BS_NBLK ((ETOT + BS_EPB - 1) / BS_EPB)

// ---------------------------------------------------------------------------
// Register-tiled GEMM + alpha epilogue. H written as fp16 (gather payload).
// ---------------------------------------------------------------------------
template<int DIN, int DOUT>
__global__ __launch_bounds__(256)
void gemm_alpha_kernel(const float* __restrict__ X, const float* __restrict__ W,
                       const float* __restrict__ a_s, const float* __restrict__ a_d,
                       __half* __restrict__ H16, float* __restrict__ asrc,
                       float* __restrict__ adst)
{
    constexpr int COLG = DOUT / 4;
    constexpr int ROWG = 256 / COLG;
    constexpr int BM   = ROWG * 4;
    constexpr int K4   = DIN / 4;

    __shared__ float Xl[BM * DIN];
    __shared__ float Wl[DIN * DOUT];

    const int tid = threadIdx.x;
    const int row0b = blockIdx.x * BM;

    constexpr int WV = DIN * DOUT / 4;
    for (int i = tid; i < WV; i += 256)
        ((float4*)Wl)[i] = ((const float4*)W)[i];

    constexpr int XV = BM * K4;
    for (int i = tid; i < XV; i += 256) {
        int r  = i / K4;
        int j  = i % K4;
        int gr = row0b + r;
        float4 v = make_float4(0.f, 0.f, 0.f, 0.f);
        if (gr < N_NODES) v = ((const float4*)X)[gr * K4 + j];
        *(float4*)&Xl[r * DIN + ((j ^ ((r >> 2) & 7)) << 2)] = v;
    }
    __syncthreads();

    const int tx = tid % COLG;
    const int ty = tid / COLG;
    const int r0 = ty * 4;
    const int c0 = tx * 4;
    const int swz = ty & 7;

    float acc[4][4] = {};
    for (int kk = 0; kk < DIN; kk += 4) {
        float a[4][4], w[4][4];
        const int jk = ((kk >> 2) ^ swz) << 2;
#pragma unroll
        for (int i = 0; i < 4; ++i)
            *(float4*)a[i] = *(const float4*)&Xl[(r0 + i) * DIN + jk];
#pragma unroll
        for (int j = 0; j < 4; ++j)
            *(float4*)w[j] = *(const float4*)&Wl[(kk + j) * DOUT + c0];
#pragma unroll
        for (int i = 0; i < 4; ++i)
#pragma unroll
            for (int j = 0; j < 4; ++j)
                acc[i][j] = fmaf(a[i][0], w[0][j],
                            fmaf(a[i][1], w[1][j],
                            fmaf(a[i][2], w[2][j],
                            fmaf(a[i][3], w[3][j], acc[i][j]))));
    }

    float as4[4], ad4[4];
    *(float4*)as4 = *(const float4*)&a_s[c0];
    *(float4*)ad4 = *(const float4*)&a_d[c0];

#pragma unroll
    for (int i = 0; i < 4; ++i) {
        const int gr = row0b + r0 + i;
        float ps = acc[i][0] * as4[0] + acc[i][1] * as4[1] +
                   acc[i][2] * as4[2] + acc[i][3] * as4[3];
        float pd = acc[i][0] * ad4[0] + acc[i][1] * ad4[1] +
                   acc[i][2] * ad4[2] + acc[i][3] * ad4[3];
#pragma unroll
        for (int off = COLG / 2; off >= 1; off >>= 1) {
            ps += __shfl_xor(ps, off, 64);
            pd += __shfl_xor(pd, off, 64);
        }
        if (gr < N_NODES) {
            __half2 p01 = __floats2half2_rn(acc[i][0], acc[i][1]);
            __half2 p23 = __floats2half2_rn(acc[i][2], acc[i][3]);
            uint2 pk;
            pk.x = *(unsigned int*)&p01;
            pk.y = *(unsigned int*)&p23;
            *(uint2*)&H16[gr * DOUT + c0] = pk;
            if (tx == 0) { asrc[gr] = ps; adst[gr] = pd; }
        }
    }
}

// ---------------------------------------------------------------------------
// CSR build: zero98 -> hist -> scan98 -> binscatter -> bucket_sort
// ---------------------------------------------------------------------------
__global__ __launch_bounds__(128)
void zero98_kernel(int* __restrict__ bcnt)
{
    int i = threadIdx.x;
    if (i < NBUCK) bcnt[i] = 0;
}

// bucket histogram (LDS-local, 98 counters)
__global__ __launch_bounds__(BS_THREADS)
void hist_kernel(const int* __restrict__ ei, int* __restrict__ bcnt)
{
    __shared__ int lcnt[NBUCK];
    const int t = threadIdx.x;
    for (int i = t; i < NBUCK; i += BS_THREADS) lcnt[i] = 0;
    __syncthreads();
    const int e0 = blockIdx.x * BS_EPB;
#pragma unroll
    for (int k = 0; k < BS_EPT; ++k) {
        const int eid = e0 + k * BS_THREADS + t;
        if (eid < ETOT) {
            int dst = (eid < E_EDGES) ? ei[E_EDGES + eid] : (eid - E_EDGES);
            atomicAdd(&lcnt[dst >> BUCK_SHIFT], 1);
        }
    }
    __syncthreads();
    for (int i = t; i < NBUCK; i += BS_THREADS)
        if (lcnt[i] > 0) atomicAdd(&bcnt[i], lcnt[i]);
}

// exclusive scan of NBUCK bucket counts -> cursors (mutable) + bases (pristine)
__global__ __launch_bounds__(128)
void scan98_kernel(const int* __restrict__ bcnt, int* __restrict__ cur,
                   int* __restrict__ cur0)
{
    __shared__ int lds[128];
    const int t = threadIdx.x;
    const int v = (t < NBUCK) ? bcnt[t] : 0;
    lds[t] = v;
    __syncthreads();
    for (int off = 1; off < 128; off <<= 1) {
        int u = (t >= off) ? lds[t - off] : 0;
        __syncthreads();
        lds[t] += u;
        __syncthreads();
    }
    if (t < NBUCK) { cur[t] = lds[t] - v; cur0[t] = lds[t] - v; }
}

// Phase A: bin edges into dst-buckets; per-(block,bucket) contiguous runs in tmp.
__global__ __launch_bounds__(BS_THREADS)
void binscatter_kernel(const int* __restrict__ ei, int* __restrict__ cur,
                       unsigned int* __restrict__ tmp)
{
    __shared__ int lcnt[NBUCK];
    __shared__ int lbase[NBUCK];
    const int t = threadIdx.x;
    for (int i = t; i < NBUCK; i += BS_THREADS) lcnt[i] = 0;
    __syncthreads();

    const int e0 = blockIdx.x * BS_EPB;
    unsigned int pk[BS_EPT];
    int rk[BS_EPT];
    int bk[BS_EPT];
#pragma unroll
    for (int k = 0; k < BS_EPT; ++k) {
        const int eid = e0 + k * BS_THREADS + t;
        bk[k] = -1;
        if (eid < ETOT) {
            int src, dst;
            if (eid < E_EDGES) { src = ei[eid]; dst = ei[E_EDGES + eid]; }
            else               { src = dst = eid - E_EDGES; }
            bk[k] = dst >> BUCK_SHIFT;
            pk[k] = ((unsigned int)dst << 16) | (unsigned int)src;
            rk[k] = atomicAdd(&lcnt[bk[k]], 1);
        }
    }
    __syncthreads();
    for (int i = t; i < NBUCK; i += BS_THREADS)
        if (lcnt[i] > 0) lbase[i] = atomicAdd(&cur[i], lcnt[i]);
    __syncthreads();
#pragma unroll
    for (int k = 0; k < BS_EPT; ++k)
        if (bk[k] >= 0) tmp[lbase[bk[k]] + rk[k]] = pk[k];
}

// Phase B: one block per bucket. LDS histogram -> LDS scan (emits offs
// directly, incl. offs[N]) -> LDS-cursor scatter into the bucket's
// contiguous csr window. All atomic contention is LDS-local.
__global__ __launch_bounds__(BUCK_SZ)
void bucket_sort_kernel(const unsigned int* __restrict__ tmp,
                        const int* __restrict__ cur0,
                        const int* __restrict__ bcnt,
                        unsigned int* __restrict__ csr_pk,
                        int* __restrict__ offs)
{
    __shared__ int lcnt[BUCK_SZ];
    __shared__ int loff[BUCK_SZ];
    __shared__ int lcur[BUCK_SZ];
    const int bk = blockIdx.x;
    const int t  = threadIdx.x;
    const int base = cur0[bk];
    const int cnt  = bcnt[bk];

    lcnt[t] = 0;
    __syncthreads();
    for (int i = t; i < cnt; i += BUCK_SZ)
        atomicAdd(&lcnt[(tmp[base + i] >> 16) & (BUCK_SZ - 1)], 1);
    __syncthreads();

    const int v = lcnt[t];
    loff[t] = v;
    __syncthreads();
    for (int off = 1; off < BUCK_SZ; off <<= 1) {
        int u = (t >= off) ? loff[t - off] : 0;
        __syncthreads();
        loff[t] += u;
        __syncthreads();
    }
    const int excl = loff[t] - v;

    const int g = (bk << BUCK_SHIFT) + t;
    if (g <= N_NODES) offs[g] = base + excl;   // tail node writes offs[N]=ETOT

    lcur[t] = excl;
    __syncthreads();
    for (int i = t; i < cnt; i += BUCK_SZ) {
        const unsigned int pk = tmp[base + i];
        const int l = (pk >> 16) & (BUCK_SZ - 1);
        const int pos = atomicAdd(&lcur[l], 1);
        csr_pk[base + pos] = pk;
    }
}

// ---------------------------------------------------------------------------
// per-layer edge scores: p = exp(leakyrelu(asrc[src] + adst[dst])), once/edge
// ---------------------------------------------------------------------------
__global__ __launch_bounds__(256)
void edge_score_kernel(const unsigned int* __restrict__ csr_pk,
                       const float* __restrict__ asrc,
                       const float* __restrict__ adst,
                       float* __restrict__ pbuf)
{
    int i = blockIdx.x * blockDim.x + threadIdx.x;
    if (i >= ETOT) return;
    const unsigned int pk = csr_pk[i];
    float v = asrc[pk & 0xffffu] + adst[pk >> 16];
    v = (v > 0.f) ? v : 0.2f * v;
    pbuf[i] = __expf(fminf(v, 80.f));
}

// ---------------------------------------------------------------------------
// node_agg v4: scores precomputed; inner loop = pk/p broadcast loads +
// one 8B fp16 H gather + 4 fma. wave = FL feature-lanes x SLOTS edge-slots.
// ---------------------------------------------------------------------------
template<int DOUT, int ACT>
__global__ __launch_bounds__(256)
void node_agg_kernel(const int* __restrict__ offs,
                     const unsigned int* __restrict__ csr_pk,
                     const float* __restrict__ pbuf,
                     const __half* __restrict__ H16,
                     const float* __restrict__ b,
                     float* __restrict__ out)
{
    constexpr int FL    = DOUT / 4;    // 16 (dout=64) or 8 (dout=32)
    constexpr int SLOTS = 64 / FL;     // 4 or 8
    const int wv   = threadIdx.x >> 6;
    const int lane = threadIdx.x & 63;
    const int fl   = lane % FL;
    const int slot = lane / FL;
    const int node = blockIdx.x * 4 + wv;
    if (node >= N_NODES) return;

    const int beg = offs[node];
    const int end = offs[node + 1];
    const __half* __restrict__ Hf = H16 + fl * 4;

    float s = 0.f;
    float4 acc = make_float4(0.f, 0.f, 0.f, 0.f);

    for (int cb = beg; cb < end; cb += SLOTS) {
        const int eid = cb + slot;
        float p = 0.f;
        uint2 h8 = make_uint2(0u, 0u);
        if (eid < end) {
            const unsigned int pk = csr_pk[eid];
            p  = pbuf[eid];
            h8 = *(const uint2*)(Hf + (pk & 0xffffu) * DOUT);
        }
        const float2 f01 = __half22float2(*(const __half2*)&h8.x);
        const float2 f23 = __half22float2(*(const __half2*)&h8.y);
        s += p;
        acc.x = fmaf(p, f01.x, acc.x);
        acc.y = fmaf(p, f01.y, acc.y);
        acc.z = fmaf(p, f23.x, acc.z);
        acc.w = fmaf(p, f23.y, acc.w);
    }

#pragma unroll
    for (int off = FL; off < 64; off <<= 1) {
        s     += __shfl_xor(s, off, 64);
        acc.x += __shfl_xor(acc.x, off, 64);
        acc.y += __shfl_xor(acc.y, off, 64);
        acc.z += __shfl_xor(acc.z, off, 64);
        acc.w += __shfl_xor(acc.w, off, 64);
    }

    if (slot == 0) {
        const float4 bb = *(const float4*)&b[fl * 4];
        const float inv = 1.f / s;
        float4 v;
        v.x = acc.x * inv + bb.x;
        v.y = acc.y * inv + bb.y;
        v.z = acc.z * inv + bb.z;
        v.w = acc.w * inv + bb.w;
        if (ACT == 0) {
            v.x = fmaxf(v.x, 0.f); v.y = fmaxf(v.y, 0.f);
            v.z = fmaxf(v.z, 0.f); v.w = fmaxf(v.w, 0.f);
        } else {
            v.x = tanhf(v.x); v.y = tanhf(v.y);
            v.z = tanhf(v.z); v.w = tanhf(v.w);
        }
        *(float4*)&out[node * DOUT + fl * 4] = v;
    }
}

// ---------------------------------------------------------------------------

template<int DIN, int DOUT, int ACT>
static void run_layer(const float* X, const float* W, const float* a_s,
                      const float* a_d, const float* b,
                      const int* offs, const unsigned int* csr_pk,
                      float* pbuf, __half* H16, float* asrc, float* adst,
                      float* out, hipStream_t stream)
{
    constexpr int COLG = DOUT / 4;
    constexpr int BM = (256 / COLG) * 4;
    const int gemm_grid = (N_NODES + BM - 1) / BM;
    gemm_alpha_kernel<DIN, DOUT><<<gemm_grid, 256, 0, stream>>>(
        X, W, a_s, a_d, H16, asrc, adst);

    const int egrid = (ETOT + 255) / 256;
    edge_score_kernel<<<egrid, 256, 0, stream>>>(csr_pk, asrc, adst, pbuf);

    const int agg_grid = (N_NODES + 3) / 4;
    node_agg_kernel<DOUT, ACT><<<agg_grid, 256, 0, stream>>>(
        offs, csr_pk, pbuf, H16, b, out);
}

extern "C" void kernel_launch(void* const* d_in, const int* in_sizes, int n_in,
                              void* d_out, int out_size, void* d_ws, size_t ws_size,
                              hipStream_t stream)
{
    const float* x  = (const float*)d_in[0];
    const int*   ei = (const int*)d_in[1];
    const float* W0 = (const float*)d_in[2];
    const float* as0= (const float*)d_in[3];
    const float* ad0= (const float*)d_in[4];
    const float* b0 = (const float*)d_in[5];
    const float* W1 = (const float*)d_in[6];
    const float* as1= (const float*)d_in[7];
    const float* ad1= (const float*)d_in[8];
    const float* b1 = (const float*)d_in[9];
    const float* W2 = (const float*)d_in[10];
    const float* as2= (const float*)d_in[11];
    const float* ad2= (const float*)d_in[12];
    const float* b2 = (const float*)d_in[13];
    float* out = (float*)d_out;

    char* wsb = (char*)d_ws;
    auto take = [&](size_t bytes) {
        char* p = wsb;
        wsb += (bytes + 255) & ~size_t(255);
        return p;
    };
    __half* h16    = (__half*)take(sizeof(__half) * N_NODES * 64);
    float* buf_act = (float*)take(sizeof(float) * N_NODES * 64);
    float* pbuf    = (float*)take(sizeof(float) * ETOT);
    float* asrc    = (float*)take(sizeof(float) * N_NODES);
    float* adst    = (float*)take(sizeof(float) * N_NODES);
    int*   offs    = (int*)take(sizeof(int) * (N_NODES + 1));
    int*   bcnt    = (int*)take(sizeof(int) * NBUCK);
    int*   cur     = (int*)take(sizeof(int) * NBUCK);
    int*   cur0    = (int*)take(sizeof(int) * NBUCK);
    unsigned int* csr_pk = (unsigned int*)take(sizeof(unsigned int) * ETOT);
    // tmp aliases h16: dead before the first gemm writes H16
    unsigned int* tmp = (unsigned int*)h16;

    const int egrid = (ETOT + 255) / 256;
    zero98_kernel<<<1, 128, 0, stream>>>(bcnt);
    hist_kernel<<<BS_NBLK, BS_THREADS, 0, stream>>>(ei, bcnt);
    scan98_kernel<<<1, 128, 0, stream>>>(bcnt, cur, cur0);
    binscatter_kernel<<<BS_NBLK, BS_THREADS, 0, stream>>>(ei, cur, tmp);
    bucket_sort_kernel<<<NBUCK, BUCK_SZ, 0, stream>>>(tmp, cur0, bcnt,
                                                      csr_pk, offs);

    run_layer<128, 64, 0>(x, W0, as0, ad0, b0, offs, csr_pk, pbuf,
                          h16, asrc, adst, buf_act, stream);
    run_layer<64, 64, 0>(buf_act, W1, as1, ad1, b1, offs, csr_pk, pbuf,
                         h16, asrc, adst, buf_act, stream);
    run_layer<64, 32, 1>(buf_act, W2, as2, ad2, b2, offs, csr_pk, pbuf,
                         h16, asrc, adst, out, stream);
}